// Round 2
// baseline (584.769 us; speedup 1.0000x reference)
//
#include <hip/hip_runtime.h>

#define NN 16384
#define MM 16384
#define DD 8
#define DV 16
#define SPLIT 32
#define CHUNK (MM / SPLIT)  // 512 columns per block

// Precompute sy[j] = sum_d ls_d * y_jd^2  (tiny: 64 KB into d_ws)
__global__ __launch_bounds__(256) void prep_sy(const float* __restrict__ ls,
                                               const float* __restrict__ y,
                                               float* __restrict__ sy) {
    int j = blockIdx.x * 256 + threadIdx.x;
    float s = 0.f;
#pragma unroll
    for (int d = 0; d < DD; ++d) {
        float yv = y[j * DD + d];
        s = fmaf(ls[d] * yv, yv, s);
    }
    sy[j] = s;
}

// One x-row per thread; each block handles 256 rows x one M-chunk of 512.
// d2 = sx + sy_j - 2 * sum_d (ls_d x_d) y_jd
// j-loop unrolled x4: four independent sqrt/exp dependence chains in flight.
__global__ __launch_bounds__(256) void matern_main(const float* __restrict__ ls,
                                                   const float* __restrict__ x,
                                                   const float* __restrict__ y,
                                                   const float* __restrict__ b,
                                                   const float* __restrict__ sy,
                                                   float* __restrict__ out) {
    const int i = blockIdx.x * 256 + threadIdx.x;
    const int jbeg = blockIdx.y * CHUNK;

    float xls[DD];
    float sx = 0.f;
#pragma unroll
    for (int d = 0; d < DD; ++d) {
        float xv = x[(size_t)i * DD + d];
        float l = ls[d];
        float xl = l * xv;
        xls[d] = xl;
        sx = fmaf(xl, xv, sx);
    }

    const float c1 = 2.23606797749979f;        // sqrt(5)
    const float c2 = 1.2909944487358056f;      // sqrt(5/3)
    const float c3 = -3.2259641843312987f;     // -sqrt(5)*log2(e): exp(-c1 r)=2^(c3 r)

    float acc[DV];
#pragma unroll
    for (int v = 0; v < DV; ++v) acc[v] = 0.f;

    const float* yp = y + (size_t)jbeg * DD;
    const float* bp = b + (size_t)jbeg * DV;
    const float* syp = sy + jbeg;

    for (int j0 = 0; j0 < CHUNK; j0 += 4) {
        float k4[4];
#pragma unroll
        for (int u = 0; u < 4; ++u) {
            const int j = j0 + u;
            float dot = 0.f;
#pragma unroll
            for (int d = 0; d < DD; ++d) dot = fmaf(xls[d], yp[j * DD + d], dot);
            float d2 = fmaf(-2.f, dot, sx + syp[j]);
            d2 = fmaxf(d2, 0.f);
            float r = __builtin_amdgcn_sqrtf(d2);
            float e = __builtin_amdgcn_exp2f(c3 * r);
            k4[u] = fmaf(c2, d2, fmaf(c1, r, 1.f)) * e;
        }
#pragma unroll
        for (int u = 0; u < 4; ++u) {
            const int j = j0 + u;
#pragma unroll
            for (int v = 0; v < DV; ++v) acc[v] = fmaf(k4[u], bp[j * DV + v], acc[v]);
        }
    }

    float* op = out + (size_t)i * DV;
#pragma unroll
    for (int v = 0; v < DV; ++v) atomicAdd(op + v, acc[v]);
}

extern "C" void kernel_launch(void* const* d_in, const int* in_sizes, int n_in,
                              void* d_out, int out_size, void* d_ws, size_t ws_size,
                              hipStream_t stream) {
    const float* ls = (const float*)d_in[0];
    const float* x  = (const float*)d_in[1];
    const float* y  = (const float*)d_in[2];
    const float* b  = (const float*)d_in[3];
    float* out = (float*)d_out;
    float* sy  = (float*)d_ws;   // 16384 floats = 64 KB scratch

    hipMemsetAsync(d_out, 0, (size_t)out_size * sizeof(float), stream);
    prep_sy<<<MM / 256, 256, 0, stream>>>(ls, y, sy);
    matern_main<<<dim3(NN / 256, SPLIT), 256, 0, stream>>>(ls, x, y, b, sy, out);
}

// Round 3
// 326.730 us; speedup vs baseline: 1.7898x; 1.7898x over previous
//
#include <hip/hip_runtime.h>

#define NN 16384
#define MM 16384
#define DD 8
#define DV 16
#define R 8                    // rows per wave
#define WAVES 4                // waves per block (256 threads)
#define ROWS_BLK (R * WAVES)   // 32 rows per block
#define JSPLIT 2
#define JCHUNK (MM / JSPLIT)   // 8192 columns per block
#define JITER (JCHUNK / 64)    // 128 lane-strided steps

// Precompute sy[j] = sum_d ls_d * y_jd^2 into d_ws (64 KB)
__global__ __launch_bounds__(256) void prep_sy(const float* __restrict__ ls,
                                               const float* __restrict__ y,
                                               float* __restrict__ sy) {
    int j = blockIdx.x * 256 + threadIdx.x;
    float s = 0.f;
#pragma unroll
    for (int d = 0; d < DD; ++d) {
        float yv = y[j * DD + d];
        s = fmaf(ls[d] * yv, yv, s);
    }
    sy[j] = s;
}

// Lane-parallel over j: wave owns 8 rows (uniform x-data in regs); lane l
// handles j = jbeg + 64*it + l. y/b/sy loads are coalesced vector VMEM
// (in-order vmcnt, pipelineable) instead of wave-uniform scalar loads
// (out-of-order SMEM forcing lgkmcnt(0) drains — the R1/R2 35%-VALUBusy stall).
// Paired .x/.y fp32 ops invite v_pk_fma_f32 (packed fp32 = 2 FLOP/lane/instr).
__global__ __launch_bounds__(256, 2) void matern_main(const float* __restrict__ ls,
                                                      const float* __restrict__ x,
                                                      const float* __restrict__ y,
                                                      const float* __restrict__ b,
                                                      const float* __restrict__ sy,
                                                      float* __restrict__ out) {
    const int lane = threadIdx.x & 63;
    const int wave = threadIdx.x >> 6;
    const int rowbase = blockIdx.x * ROWS_BLK + wave * R;
    const int jbeg = blockIdx.y * JCHUNK;

    // Wave-uniform per-row data: xls[r][d] = ls_d * x_rd ; sx_r = sum ls_d x_rd^2
    float2 xls[R][4];
    float sxr[R];
    {
        float lsv[DD];
#pragma unroll
        for (int d = 0; d < DD; ++d) lsv[d] = ls[d];
#pragma unroll
        for (int r = 0; r < R; ++r) {
            const float* xp = x + (size_t)(rowbase + r) * DD;
            float s = 0.f;
#pragma unroll
            for (int dd = 0; dd < 4; ++dd) {
                float x0 = xp[2 * dd], x1 = xp[2 * dd + 1];
                float xl0 = lsv[2 * dd] * x0, xl1 = lsv[2 * dd + 1] * x1;
                xls[r][dd].x = xl0;
                xls[r][dd].y = xl1;
                s = fmaf(xl0, x0, s);
                s = fmaf(xl1, x1, s);
            }
            sxr[r] = s;
        }
    }

    const float c1 = 2.23606797749979f;       // sqrt(5)
    const float c2 = 1.2909944487358056f;     // sqrt(5/3)
    const float c3 = -3.2259641843312987f;    // -sqrt(5)*log2(e)

    float2 acc[R][8];
#pragma unroll
    for (int r = 0; r < R; ++r)
#pragma unroll
        for (int v = 0; v < 8; ++v) acc[r][v] = make_float2(0.f, 0.f);

    const float4* y4 = (const float4*)y;
    const float4* b4 = (const float4*)b;

#pragma unroll 1
    for (int it = 0; it < JITER; ++it) {
        const size_t j = (size_t)jbeg + (size_t)it * 64 + lane;
        float4 ya = y4[j * 2 + 0];
        float4 yb = y4[j * 2 + 1];
        float syv = sy[j];
        float4 b0 = b4[j * 4 + 0];
        float4 b1 = b4[j * 4 + 1];
        float4 b2 = b4[j * 4 + 2];
        float4 b3 = b4[j * 4 + 3];

#pragma unroll
        for (int r = 0; r < R; ++r) {
            float dx = xls[r][0].x * ya.x;
            float dy = xls[r][0].y * ya.y;
            dx = fmaf(xls[r][1].x, ya.z, dx);
            dy = fmaf(xls[r][1].y, ya.w, dy);
            dx = fmaf(xls[r][2].x, yb.x, dx);
            dy = fmaf(xls[r][2].y, yb.y, dy);
            dx = fmaf(xls[r][3].x, yb.z, dx);
            dy = fmaf(xls[r][3].y, yb.w, dy);
            float dot = dx + dy;
            float d2 = fmaf(-2.f, dot, sxr[r] + syv);
            d2 = fmaxf(d2, 0.f);
            float rr = __builtin_amdgcn_sqrtf(d2);
            float e = __builtin_amdgcn_exp2f(c3 * rr);
            float k = fmaf(c2, d2, fmaf(c1, rr, 1.f)) * e;

            acc[r][0].x = fmaf(k, b0.x, acc[r][0].x);
            acc[r][0].y = fmaf(k, b0.y, acc[r][0].y);
            acc[r][1].x = fmaf(k, b0.z, acc[r][1].x);
            acc[r][1].y = fmaf(k, b0.w, acc[r][1].y);
            acc[r][2].x = fmaf(k, b1.x, acc[r][2].x);
            acc[r][2].y = fmaf(k, b1.y, acc[r][2].y);
            acc[r][3].x = fmaf(k, b1.z, acc[r][3].x);
            acc[r][3].y = fmaf(k, b1.w, acc[r][3].y);
            acc[r][4].x = fmaf(k, b2.x, acc[r][4].x);
            acc[r][4].y = fmaf(k, b2.y, acc[r][4].y);
            acc[r][5].x = fmaf(k, b2.z, acc[r][5].x);
            acc[r][5].y = fmaf(k, b2.w, acc[r][5].y);
            acc[r][6].x = fmaf(k, b3.x, acc[r][6].x);
            acc[r][6].y = fmaf(k, b3.y, acc[r][6].y);
            acc[r][7].x = fmaf(k, b3.z, acc[r][7].x);
            acc[r][7].y = fmaf(k, b3.w, acc[r][7].y);
        }
    }

    // Butterfly-reduce each accumulator across the 64 lanes.
#pragma unroll
    for (int r = 0; r < R; ++r)
#pragma unroll
        for (int v = 0; v < 8; ++v) {
            float px = acc[r][v].x, py = acc[r][v].y;
#pragma unroll
            for (int off = 32; off > 0; off >>= 1) {
                px += __shfl_xor(px, off, 64);
                py += __shfl_xor(py, off, 64);
            }
            acc[r][v].x = px;
            acc[r][v].y = py;
        }

    if (lane == 0) {
#pragma unroll
        for (int r = 0; r < R; ++r) {
            float* op = out + (size_t)(rowbase + r) * DV;
#pragma unroll
            for (int v = 0; v < 8; ++v) {
                atomicAdd(op + 2 * v, acc[r][v].x);
                atomicAdd(op + 2 * v + 1, acc[r][v].y);
            }
        }
    }
}

extern "C" void kernel_launch(void* const* d_in, const int* in_sizes, int n_in,
                              void* d_out, int out_size, void* d_ws, size_t ws_size,
                              hipStream_t stream) {
    const float* ls = (const float*)d_in[0];
    const float* x  = (const float*)d_in[1];
    const float* y  = (const float*)d_in[2];
    const float* b  = (const float*)d_in[3];
    float* out = (float*)d_out;
    float* sy  = (float*)d_ws;   // 16384 floats = 64 KB scratch

    hipMemsetAsync(d_out, 0, (size_t)out_size * sizeof(float), stream);
    prep_sy<<<MM / 256, 256, 0, stream>>>(ls, y, sy);
    matern_main<<<dim3(NN / ROWS_BLK, JSPLIT), 256, 0, stream>>>(ls, x, y, b, sy, out);
}